// Round 9
// baseline (1096.358 us; speedup 1.0000x reference)
//
#include <hip/hip_runtime.h>
#include <hip/hip_bf16.h>
#include <math.h>

#define B_ 8
#define T_ 8192
#define V_ 256
#define EB_ 64
#define E_ 64
#define H_ 512
#define SS_ 32
#define FEATP_ 192   // padded feature dim (real 132, zero-padded to 192 = 3*64 for BK=64 core)
#define NCH_ 256
#define CHUNK_ 32

typedef __attribute__((ext_vector_type(8))) short bf8;     // 8 bf16 = 4 VGPRs (MFMA A/B frag)
typedef __attribute__((ext_vector_type(16))) float accv;   // MFMA 32x32 C/D frag

#define AS1(p) (__attribute__((address_space(1))) void*)(void*)(p)
#define AS3(p) (__attribute__((address_space(3))) void*)(void*)(p)

__device__ __forceinline__ float silu_f(float x) { return x / (1.0f + expf(-x)); }
__device__ __forceinline__ float sigm_f(float x) { return 1.0f / (1.0f + expf(-x)); }
__device__ __forceinline__ float bf2f(__hip_bfloat16 v) { return __bfloat162float(v); }
__device__ __forceinline__ __hip_bfloat16 f2bf(float v) { return __float2bfloat16(v); }
__device__ __forceinline__ float us2f(ushort u) {
    union { float f; unsigned int u32; } c; c.u32 = ((unsigned int)u) << 16; return c.f;
}
__device__ __forceinline__ ushort f2us(float v) {
    __hip_bfloat16 t = __float2bfloat16(v);
    return *reinterpret_cast<ushort*>(&t);
}
__device__ __forceinline__ float rdlane(float v, int l) {
    return __int_as_float(__builtin_amdgcn_readlane(__float_as_int(v), l));
}

#define CD_ROW(r, lane) (((r) & 3) + 8 * ((r) >> 2) + 4 * ((lane) >> 5))

// bijective XCD-chunk swizzle (nwg % 8 == 0): neighbor wgids land on same XCD L2
__device__ __forceinline__ int xcd_swz(int bid, int nwg) {
    return (bid & 7) * (nwg >> 3) + (bid >> 3);
}

// ===================== 256x256 MFMA core (R5-verified, 73us/mlp) =====================
template <int KD>
__device__ __forceinline__ void mm256(const ushort* __restrict__ Ab,
                                      const ushort* __restrict__ Bb,
                                      int m0, int n0, accv (&acc)[4][2]) {
    constexpr int NT = KD / 64;
    __shared__ __align__(1024) ushort lA[33280];   // 66560 B: 2 slots x 32 grp x 520us
    __shared__ __align__(1024) ushort lB[33280];
    const int tid  = threadIdx.x;
    const int lane = tid & 63;
    const int w    = tid >> 6;
    const int wm   = w >> 2, wn = w & 3;
    const int l31  = lane & 31, lh = lane >> 5;

    const int srow = lane >> 3;                          // 0..7
    const int scg  = (lane & 7) ^ ((srow & 1) << 2);     // 64B-half swap only
    const ushort* gA = Ab + (size_t)(m0 + w * 32 + srow) * KD + scg * 8;
    const ushort* gB = Bb + (size_t)(n0 + w * 32 + srow) * KD + scg * 8;
    const int dgrp = w * 4;

    const int rbase = (l31 >> 3) * 520 + (l31 & 7) * 64;
    int oK[4];
#pragma unroll
    for (int ks = 0; ks < 4; ks++) oK[ks] = (((ks * 2 + lh) ^ ((l31 & 1) << 2)) << 3);
    const int aoff = wm * 8320 + rbase;
    const int boff = wn * 4160 + rbase;

#define STG8(slot, kt)                                                                             \
    do {                                                                                           \
        __builtin_amdgcn_global_load_lds(AS1(gA + (kt)),                                           \
                                         AS3(&lA[(slot) * 16640 + (dgrp + 0) * 520]), 16, 0, 0);   \
        __builtin_amdgcn_global_load_lds(AS1(gB + (kt)),                                           \
                                         AS3(&lB[(slot) * 16640 + (dgrp + 0) * 520]), 16, 0, 0);   \
        __builtin_amdgcn_global_load_lds(AS1(gA + (size_t)8 * KD + (kt)),                          \
                                         AS3(&lA[(slot) * 16640 + (dgrp + 1) * 520]), 16, 0, 0);   \
        __builtin_amdgcn_global_load_lds(AS1(gB + (size_t)8 * KD + (kt)),                          \
                                         AS3(&lB[(slot) * 16640 + (dgrp + 1) * 520]), 16, 0, 0);   \
        __builtin_amdgcn_global_load_lds(AS1(gA + (size_t)16 * KD + (kt)),                         \
                                         AS3(&lA[(slot) * 16640 + (dgrp + 2) * 520]), 16, 0, 0);   \
        __builtin_amdgcn_global_load_lds(AS1(gB + (size_t)16 * KD + (kt)),                         \
                                         AS3(&lB[(slot) * 16640 + (dgrp + 2) * 520]), 16, 0, 0);   \
        __builtin_amdgcn_global_load_lds(AS1(gA + (size_t)24 * KD + (kt)),                         \
                                         AS3(&lA[(slot) * 16640 + (dgrp + 3) * 520]), 16, 0, 0);   \
        __builtin_amdgcn_global_load_lds(AS1(gB + (size_t)24 * KD + (kt)),                         \
                                         AS3(&lB[(slot) * 16640 + (dgrp + 3) * 520]), 16, 0, 0);   \
    } while (0)

#define PH(slot, ks)                                                                               \
    do {                                                                                           \
        const ushort* pa = &lA[(slot) * 16640 + aoff + oK[ks]];                                    \
        const ushort* pb = &lB[(slot) * 16640 + boff + oK[ks]];                                    \
        bf8 b0v = *(const bf8*)(pb);                                                               \
        bf8 b1v = *(const bf8*)(pb + 2080);                                                        \
        bf8 a0v = *(const bf8*)(pa);                                                               \
        bf8 a1v = *(const bf8*)(pa + 2080);                                                        \
        bf8 a2v = *(const bf8*)(pa + 4160);                                                        \
        bf8 a3v = *(const bf8*)(pa + 6240);                                                        \
        acc[0][0] = __builtin_amdgcn_mfma_f32_32x32x16_bf16(a0v, b0v, acc[0][0], 0, 0, 0);         \
        acc[0][1] = __builtin_amdgcn_mfma_f32_32x32x16_bf16(a0v, b1v, acc[0][1], 0, 0, 0);         \
        acc[1][0] = __builtin_amdgcn_mfma_f32_32x32x16_bf16(a1v, b0v, acc[1][0], 0, 0, 0);         \
        acc[1][1] = __builtin_amdgcn_mfma_f32_32x32x16_bf16(a1v, b1v, acc[1][1], 0, 0, 0);         \
        acc[2][0] = __builtin_amdgcn_mfma_f32_32x32x16_bf16(a2v, b0v, acc[2][0], 0, 0, 0);         \
        acc[2][1] = __builtin_amdgcn_mfma_f32_32x32x16_bf16(a2v, b1v, acc[2][1], 0, 0, 0);         \
        acc[3][0] = __builtin_amdgcn_mfma_f32_32x32x16_bf16(a3v, b0v, acc[3][0], 0, 0, 0);         \
        acc[3][1] = __builtin_amdgcn_mfma_f32_32x32x16_bf16(a3v, b1v, acc[3][1], 0, 0, 0);         \
    } while (0)

    STG8(0, 0);
#pragma unroll
    for (int t = 0; t < NT - 1; ++t) {
        const int slot = t & 1;
        STG8(slot ^ 1, (t + 1) * 64);
        asm volatile("s_waitcnt vmcnt(8)" ::: "memory");
        __builtin_amdgcn_s_barrier();
        __builtin_amdgcn_sched_barrier(0);
        __builtin_amdgcn_s_setprio(1);
        PH(slot, 0); PH(slot, 1); PH(slot, 2); PH(slot, 3);
        __builtin_amdgcn_s_setprio(0);
        __builtin_amdgcn_s_barrier();
    }
    asm volatile("s_waitcnt vmcnt(0)" ::: "memory");
    __builtin_amdgcn_s_barrier();
    __builtin_amdgcn_sched_barrier(0);
    {
        const int ls = (NT - 1) & 1;
        __builtin_amdgcn_s_setprio(1);
        PH(ls, 0); PH(ls, 1); PH(ls, 2); PH(ls, 3);
        __builtin_amdgcn_s_setprio(0);
    }
#undef STG8
#undef PH
}

__device__ __forceinline__ void zero_acc8(accv (&acc)[4][2]) {
#pragma unroll
    for (int i = 0; i < 4; i++)
#pragma unroll
        for (int j = 0; j < 2; j++)
#pragma unroll
            for (int r = 0; r < 16; r++) acc[i][j][r] = 0.0f;
}

// ---------------- MLP residual block: hout = hin + silu(hin @ W + b)
__global__ __launch_bounds__(512, 2) void k_mlp256(const __hip_bfloat16* __restrict__ hin,
                                                   const __hip_bfloat16* __restrict__ Wt,
                                                   const float* __restrict__ bias,
                                                   __hip_bfloat16* __restrict__ hout) {
    accv acc[4][2];
    zero_acc8(acc);
    int wg = xcd_swz(blockIdx.x, 512);
    int m0 = (wg >> 1) * 256, n0 = (wg & 1) * 256;
    int lane = threadIdx.x & 63, w = threadIdx.x >> 6, wm = w >> 2, wn = w & 3;
    mm256<H_>((const ushort*)hin, (const ushort*)Wt, m0, n0, acc);
#pragma unroll
    for (int fr = 0; fr < 4; fr++)
#pragma unroll
        for (int fc = 0; fc < 2; fc++) {
            int col = n0 + 64 * wn + 32 * fc + (lane & 31);
            float bv = bias[col];
#pragma unroll
            for (int r = 0; r < 16; r++) {
                int row = m0 + 128 * wm + 32 * fr + CD_ROW(r, lane);
                float v = acc[fr][fc][r] + bv;
                float res = bf2f(hin[(size_t)row * H_ + col]);
                hout[(size_t)row * H_ + col] = f2bf(res + silu_f(v));
            }
        }
}

// ---------------- Win: hb = bf16(silu(featb @ Win + b_in)), KD=192 (zero-padded)
__global__ __launch_bounds__(512, 2) void k_win256(const __hip_bfloat16* __restrict__ featb,
                                                   const __hip_bfloat16* __restrict__ Wt,
                                                   const float* __restrict__ bias,
                                                   __hip_bfloat16* __restrict__ hb) {
    accv acc[4][2];
    zero_acc8(acc);
    int wg = xcd_swz(blockIdx.x, 512);
    int m0 = (wg >> 1) * 256, n0 = (wg & 1) * 256;
    int lane = threadIdx.x & 63, w = threadIdx.x >> 6, wm = w >> 2, wn = w & 3;
    mm256<FEATP_>((const ushort*)featb, (const ushort*)Wt, m0, n0, acc);
#pragma unroll
    for (int fr = 0; fr < 4; fr++)
#pragma unroll
        for (int fc = 0; fc < 2; fc++) {
            int col = n0 + 64 * wn + 32 * fc + (lane & 31);
            float bv = bias[col];
#pragma unroll
            for (int r = 0; r < 16; r++) {
                int row = m0 + 128 * wm + 32 * fr + CD_ROW(r, lane);
                hb[(size_t)row * H_ + col] = f2bf(silu_f(acc[fr][fc][r] + bv));
            }
        }
}

// ---------------- Out: out = hb @ Wout + bout (fp32 out, N=256 single n-block)
__global__ __launch_bounds__(512, 2) void k_out256(const __hip_bfloat16* __restrict__ hb,
                                                   const __hip_bfloat16* __restrict__ Wt,
                                                   const float* __restrict__ bout,
                                                   float* __restrict__ out) {
    accv acc[4][2];
    zero_acc8(acc);
    int wg = xcd_swz(blockIdx.x, 256);
    int m0 = wg * 256;
    int lane = threadIdx.x & 63, w = threadIdx.x >> 6, wm = w >> 2, wn = w & 3;
    mm256<H_>((const ushort*)hb, (const ushort*)Wt, m0, 0, acc);
#pragma unroll
    for (int fr = 0; fr < 4; fr++)
#pragma unroll
        for (int fc = 0; fc < 2; fc++) {
            int col = 64 * wn + 32 * fc + (lane & 31);
            float bv = bout[col];
#pragma unroll
            for (int r = 0; r < 16; r++) {
                int row = m0 + 128 * wm + 32 * fr + CD_ROW(r, lane);
                out[(size_t)row * V_ + col] = acc[fr][fc][r] + bv;
            }
        }
}

// ===================== FUSED womm+LN (VALU, no tmp round-trip) =====================
// h_out[tok] = LN( h_in[tok] + states[tok] @ Wo + bo )
// R8 lesson: the LN epilogue LAMBDA took the accumulator arrays BY REFERENCE ->
// address-taken arrays defeat SROA -> scratch (VGPR stuck at 128, 1.2GB spill
// traffic, rule #20 family). Fix: LN as a MACRO, all literal indices, no
// addresses taken. Everything else identical to R8.
#define LN_STORE(ax, tok)                                                                   \
    do {                                                                                    \
        float sm = ax[0] + ax[1] + ax[2] + ax[3] + ax[4] + ax[5] + ax[6] + ax[7];           \
        float sq = ax[0]*ax[0] + ax[1]*ax[1] + ax[2]*ax[2] + ax[3]*ax[3]                    \
                 + ax[4]*ax[4] + ax[5]*ax[5] + ax[6]*ax[6] + ax[7]*ax[7];                   \
        sm += __shfl_xor(sm, 32, 64); sq += __shfl_xor(sq, 32, 64);                         \
        sm += __shfl_xor(sm, 16, 64); sq += __shfl_xor(sq, 16, 64);                         \
        sm += __shfl_xor(sm, 8, 64);  sq += __shfl_xor(sq, 8, 64);                          \
        sm += __shfl_xor(sm, 4, 64);  sq += __shfl_xor(sq, 4, 64);                          \
        sm += __shfl_xor(sm, 2, 64);  sq += __shfl_xor(sq, 2, 64);                          \
        sm += __shfl_xor(sm, 1, 64);  sq += __shfl_xor(sq, 1, 64);                          \
        float mu = sm * (1.0f / 512.0f);                                                    \
        float var = sq * (1.0f / 512.0f) - mu * mu;                                         \
        float rstd = rsqrtf(fmaxf(var, 0.0f) + 1e-5f);                                      \
        bf8 o;                                                                              \
        o[0] = (short)f2us((ax[0] - mu) * rstd * gg0 + bb0);                                \
        o[1] = (short)f2us((ax[1] - mu) * rstd * gg1 + bb1);                                \
        o[2] = (short)f2us((ax[2] - mu) * rstd * gg2 + bb2);                                \
        o[3] = (short)f2us((ax[3] - mu) * rstd * gg3 + bb3);                                \
        o[4] = (short)f2us((ax[4] - mu) * rstd * gg4 + bb4);                                \
        o[5] = (short)f2us((ax[5] - mu) * rstd * gg5 + bb5);                                \
        o[6] = (short)f2us((ax[6] - mu) * rstd * gg6 + bb6);                                \
        o[7] = (short)f2us((ax[7] - mu) * rstd * gg7 + bb7);                                \
        *(bf8*)(Ob + (size_t)(tok) * 512 + lane * 8) = o;                                   \
    } while (0)

__global__ __launch_bounds__(512, 2) void k_wln(
    const __hip_bfloat16* __restrict__ states_bf,
    const __hip_bfloat16* __restrict__ Wo2,       // [32][512] bf16
    const float* __restrict__ bo,
    const __hip_bfloat16* __restrict__ h_in,
    const float* __restrict__ ln_g,
    const float* __restrict__ ln_b,
    __hip_bfloat16* __restrict__ h_out) {
    __shared__ __align__(1024) ushort lW[16384];   // 32 KiB
    const int tid = threadIdx.x, lane = tid & 63, w = tid >> 6;

    // stage Wo2 -> LDS: wave w covers bytes [w*4096, w*4096+4096), 4 instrs
    {
        const ushort* srcw = (const ushort*)Wo2 + w * 2048 + lane * 8;   // per-lane src
        ushort* dstw = &lW[w * 2048];                                     // wave-uniform dst
#pragma unroll
        for (int i = 0; i < 4; ++i)
            __builtin_amdgcn_global_load_lds(AS1(srcw + i * 512), AS3(dstw + i * 512), 16, 0, 0);
    }

    // per-lane constants (cols lane*8 .. lane*8+7) — all NAMED scalars
    float4 g0 = *(const float4*)(ln_g + lane * 8);
    float4 g1 = *(const float4*)(ln_g + lane * 8 + 4);
    float4 lb0 = *(const float4*)(ln_b + lane * 8);
    float4 lb1 = *(const float4*)(ln_b + lane * 8 + 4);
    float4 bo0 = *(const float4*)(bo + lane * 8);
    float4 bo1 = *(const float4*)(bo + lane * 8 + 4);
    float gg0 = g0.x, gg1 = g0.y, gg2 = g0.z, gg3 = g0.w;
    float gg4 = g1.x, gg5 = g1.y, gg6 = g1.z, gg7 = g1.w;
    float bb0 = lb0.x, bb1 = lb0.y, bb2 = lb0.z, bb3 = lb0.w;
    float bb4 = lb1.x, bb5 = lb1.y, bb6 = lb1.z, bb7 = lb1.w;
    float bv0 = bo0.x, bv1 = bo0.y, bv2 = bo0.z, bv3 = bo0.w;
    float bv4 = bo1.x, bv5 = bo1.y, bv6 = bo1.z, bv7 = bo1.w;

    asm volatile("s_waitcnt vmcnt(0)" ::: "memory");
    __syncthreads();

    const ushort* Sb = (const ushort*)states_bf;
    const ushort* Hb = (const ushort*)h_in;
    ushort* Ob = (ushort*)h_out;

    // wave w owns tokens [bid*64 + w*8, +8), 2 per pass
    for (int pass = 0; pass < 4; ++pass) {
        const int tok0 = blockIdx.x * 64 + w * 8 + pass * 2;
        // states rows: 2 tokens x 32 bf16; lanes 0-31 tok0, 32-63 tok1
        float sv = us2f(Sb[(size_t)tok0 * 32 + lane]);
        // h rows + bias -> fp32 acc
        const ushort* h0 = Hb + (size_t)tok0 * 512 + lane * 8;
        float a0[8], a1[8];
        {
            uint4 u0 = *(const uint4*)(h0);
            uint4 u1 = *(const uint4*)(h0 + 512);
            a0[0] = __uint_as_float(u0.x << 16) + bv0;
            a0[1] = __uint_as_float(u0.x & 0xffff0000u) + bv1;
            a0[2] = __uint_as_float(u0.y << 16) + bv2;
            a0[3] = __uint_as_float(u0.y & 0xffff0000u) + bv3;
            a0[4] = __uint_as_float(u0.z << 16) + bv4;
            a0[5] = __uint_as_float(u0.z & 0xffff0000u) + bv5;
            a0[6] = __uint_as_float(u0.w << 16) + bv6;
            a0[7] = __uint_as_float(u0.w & 0xffff0000u) + bv7;
            a1[0] = __uint_as_float(u1.x << 16) + bv0;
            a1[1] = __uint_as_float(u1.x & 0xffff0000u) + bv1;
            a1[2] = __uint_as_float(u1.y << 16) + bv2;
            a1[3] = __uint_as_float(u1.y & 0xffff0000u) + bv3;
            a1[4] = __uint_as_float(u1.z << 16) + bv4;
            a1[5] = __uint_as_float(u1.z & 0xffff0000u) + bv5;
            a1[6] = __uint_as_float(u1.w << 16) + bv6;
            a1[7] = __uint_as_float(u1.w & 0xffff0000u) + bv7;
        }
        // womm: acc += states @ Wo   (lane-broadcast FMA)
#pragma unroll
        for (int k = 0; k < 32; ++k) {
            uint4 wu = *(const uint4*)&lW[k * 512 + lane * 8];
            float s0k = rdlane(sv, k);
            float s1k = rdlane(sv, 32 + k);
            float wf0 = __uint_as_float(wu.x << 16);
            float wf1 = __uint_as_float(wu.x & 0xffff0000u);
            float wf2 = __uint_as_float(wu.y << 16);
            float wf3 = __uint_as_float(wu.y & 0xffff0000u);
            float wf4 = __uint_as_float(wu.z << 16);
            float wf5 = __uint_as_float(wu.z & 0xffff0000u);
            float wf6 = __uint_as_float(wu.w << 16);
            float wf7 = __uint_as_float(wu.w & 0xffff0000u);
            a0[0] = fmaf(s0k, wf0, a0[0]); a1[0] = fmaf(s1k, wf0, a1[0]);
            a0[1] = fmaf(s0k, wf1, a0[1]); a1[1] = fmaf(s1k, wf1, a1[1]);
            a0[2] = fmaf(s0k, wf2, a0[2]); a1[2] = fmaf(s1k, wf2, a1[2]);
            a0[3] = fmaf(s0k, wf3, a0[3]); a1[3] = fmaf(s1k, wf3, a1[3]);
            a0[4] = fmaf(s0k, wf4, a0[4]); a1[4] = fmaf(s1k, wf4, a1[4]);
            a0[5] = fmaf(s0k, wf5, a0[5]); a1[5] = fmaf(s1k, wf5, a1[5]);
            a0[6] = fmaf(s0k, wf6, a0[6]); a1[6] = fmaf(s1k, wf6, a1[6]);
            a0[7] = fmaf(s0k, wf7, a0[7]); a1[7] = fmaf(s1k, wf7, a1[7]);
        }
        // LN per token (full 512-col row spans the wave) + store — MACRO, no lambda
        LN_STORE(a0, tok0);
        LN_STORE(a1, tok0 + 1);
    }
}

// ---------------- gates/drive: [g|i] = hb @ [Wg|Wi]; tile 256x64, K=512
__global__ __launch_bounds__(256) void k_gates_mfma(const __hip_bfloat16* __restrict__ hb,
                                                    const __hip_bfloat16* __restrict__ Wt_gd,
                                                    const float* __restrict__ bg,
                                                    const float* __restrict__ bi,
                                                    float* __restrict__ gates,
                                                    float* __restrict__ drive) {
    __shared__ __align__(16) ushort lA[256 * 32];
    __shared__ __align__(16) ushort lB[64 * 32];
    int tid = threadIdx.x, lane = tid & 63, w = tid >> 6;
    int m0 = blockIdx.x * 256;
    accv acc[2][2];
#pragma unroll
    for (int i = 0; i < 2; i++)
#pragma unroll
        for (int j = 0; j < 2; j++)
#pragma unroll
            for (int r = 0; r < 16; r++) acc[i][j][r] = 0.0f;
    const ushort* Ab = (const ushort*)hb;
    const ushort* Bb = (const ushort*)Wt_gd;
    const ushort* pa = &lA[(64 * w + (lane & 31)) * 32 + (lane >> 5) * 8];
    const ushort* pb = &lB[((lane & 31)) * 32 + (lane >> 5) * 8];
    int cb = w * 64 + lane;
    const ushort* gB = Bb + (size_t)(cb >> 2) * H_ + (cb & 3) * 8;
    for (int kt = 0; kt < H_; kt += 32) {
#pragma unroll
        for (int j = 0; j < 4; j++) {
            int c = w * 256 + j * 64 + lane;
            __builtin_amdgcn_global_load_lds(
                AS1(Ab + (size_t)(m0 + (c >> 2)) * H_ + (c & 3) * 8 + kt),
                AS3(&lA[(w * 256 + j * 64) * 8]), 16, 0, 0);
        }
        __builtin_amdgcn_global_load_lds(AS1(gB + kt), AS3(&lB[(w * 64) * 8]), 16, 0, 0);
        __syncthreads();
#pragma unroll
        for (int ks = 0; ks < 2; ks++) {
            bf8 a0 = *(const bf8*)(pa + ks * 16);
            bf8 a1 = *(const bf8*)(pa + 32 * 32 + ks * 16);
            bf8 b0 = *(const bf8*)(pb + ks * 16);
            bf8 b1 = *(const bf8*)(pb + 32 * 32 + ks * 16);
            acc[0][0] = __builtin_amdgcn_mfma_f32_32x32x16_bf16(a0, b0, acc[0][0], 0, 0, 0);
            acc[0][1] = __builtin_amdgcn_mfma_f32_32x32x16_bf16(a0, b1, acc[0][1], 0, 0, 0);
            acc[1][0] = __builtin_amdgcn_mfma_f32_32x32x16_bf16(a1, b0, acc[1][0], 0, 0, 0);
            acc[1][1] = __builtin_amdgcn_mfma_f32_32x32x16_bf16(a1, b1, acc[1][1], 0, 0, 0);
        }
        __syncthreads();
    }
    int c = lane & 31;
    float bgv = bg[c], biv = bi[c];
#pragma unroll
    for (int i = 0; i < 2; i++)
#pragma unroll
        for (int r = 0; r < 16; r++) {
            int row = m0 + 64 * w + 32 * i + CD_ROW(r, lane);
            float g = sigm_f(acc[i][0][r] + bgv);
            float d = (1.0f - g) * (acc[i][1][r] + biv);
            gates[(size_t)row * SS_ + c] = g;
            drive[(size_t)row * SS_ + c] = d;
        }
}

// ===================== weight prep: bf16 + transpose + Qtab =====================
// regions: mlp[0,786432) out[786432,917504) win[917504,1015808) gd[1015808,1048576)
//          wo[1048576,1064960) qtab[1064960,1081344) wo2[1081344,1097728)
__global__ __launch_bounds__(256) void k_prep_w(const float* __restrict__ mlp_w,
                                                const float* __restrict__ Wout,
                                                const float* __restrict__ Win,
                                                const float* __restrict__ Wg,
                                                const float* __restrict__ Wi,
                                                const float* __restrict__ Wo,
                                                const float* __restrict__ Wq,
                                                const float* __restrict__ bq,
                                                const float* __restrict__ emb_byte,
                                                __hip_bfloat16* __restrict__ Wt_mlp,
                                                __hip_bfloat16* __restrict__ Wt_out,
                                                __hip_bfloat16* __restrict__ Wt_win,
                                                __hip_bfloat16* __restrict__ Wt_gd,
                                                __hip_bfloat16* __restrict__ Wt_wo,
                                                float* __restrict__ Qtab,
                                                __hip_bfloat16* __restrict__ Wt_wo2) {
    int idx = blockIdx.x * 256 + threadIdx.x;
    if (idx < 786432) {
        int l = idx >> 18, rem = idx & 262143;
        int n = rem >> 9, k = rem & 511;
        Wt_mlp[idx] = f2bf(mlp_w[l * 262144 + k * 512 + n]);
    } else if (idx < 917504) {
        int rem = idx - 786432;
        int n = rem >> 9, k = rem & 511;
        Wt_out[rem] = f2bf(Wout[k * 256 + n]);
    } else if (idx < 1015808) {
        int rem = idx - 917504;
        int n = rem / FEATP_, k = rem % FEATP_;
        Wt_win[rem] = f2bf(k < 132 ? Win[k * 512 + n] : 0.0f);
    } else if (idx < 1048576) {
        int rem = idx - 1015808;
        int n = rem >> 9, k = rem & 511;
        Wt_gd[rem] = f2bf(n < 32 ? Wg[k * 32 + n] : Wi[k * 32 + (n - 32)]);
    } else if (idx < 1064960) {
        int rem = idx - 1048576;
        int n = rem >> 5, k = rem & 31;
        Wt_wo[rem] = f2bf(Wo[k * H_ + n]);
    } else if (idx < 1081344) {
        int rem = idx - 1064960;
        int c = rem >> 6, e = rem & 63;
        float a = bq[e];
#pragma unroll 8
        for (int k = 0; k < 64; k++) a += emb_byte[c * 64 + k] * Wq[k * 64 + e];
        Qtab[rem] = a * 0.125f;   // fold 1/sqrt(E) score scale
    } else if (idx < 1097728) {
        int rem = idx - 1081344;           // [k][c] natural layout for k_wln
        Wt_wo2[rem] = f2bf(Wo[rem]);       // Wo is (32,512) row-major already
    }
}

// ===================== token features (Qtab-based, no matvec) =====================
__global__ __launch_bounds__(256) void k_token_feats(
    const int* __restrict__ chars, const float* __restrict__ emb_byte,
    const float* __restrict__ hash_tables, const float* __restrict__ Qtab,
    __hip_bfloat16* __restrict__ featb, float* __restrict__ hfpre) {
    int wave = threadIdx.x >> 6, lane = threadIdx.x & 63;
    int token = blockIdx.x * 4 + wave;
    int t = token & (T_ - 1);
    int b = token >> 13;
    const int* crow = chars + b * T_;
    int cv[16];
#pragma unroll
    for (int j = 0; j < 16; j++) cv[j] = (t >= j) ? crow[t - j] : 0;
    int acc = 0;
    int hidx[4];
#pragma unroll
    for (int j = 0; j < 16; j++) {
        acc += cv[j] * (1 + 256 * j);
        if (j == 1) hidx[0] = acc & 4095;
        if (j == 3) hidx[1] = acc & 4095;
        if (j == 7) hidx[2] = acc & 4095;
        if (j == 15) hidx[3] = acc & 4095;
    }
    int c0 = cv[0];
    float be = emb_byte[c0 * EB_ + lane];
    float q = Qtab[c0 * 64 + lane];
    float se[4];
#pragma unroll
    for (int s = 0; s < 4; s++) se[s] = hash_tables[(s * 4096 + hidx[s]) * E_ + lane];
    float sc[4];
#pragma unroll
    for (int s = 0; s < 4; s++) {
        float v = q * se[s];
#pragma unroll
        for (int off = 32; off; off >>= 1) v += __shfl_xor(v, off, 64);
        sc[s] = v;
    }
    float mx = fmaxf(fmaxf(sc[0], sc[1]), fmaxf(sc[2], sc[3]));
    float w0 = expf(sc[0] - mx), w1 = expf(sc[1] - mx), w2 = expf(sc[2] - mx), w3 = expf(sc[3] - mx);
    float inv = 1.0f / (w0 + w1 + w2 + w3);
    float hf = (w0 * se[0] + w1 * se[1] + w2 * se[2] + w3 * se[3]) * inv;
    featb[(size_t)token * FEATP_ + lane] = f2bf(be);
    hfpre[(size_t)token * E_ + lane] = hf;
    if (lane < 32) {
        float m = 0.0f;
        if (lane < 4) {
            int k = 1 << lane;
            m = (t >= k && c0 == cv[k]) ? 1.0f : 0.0f;
        }
        featb[(size_t)token * FEATP_ + 128 + lane] = f2bf(m);
    } else {
        featb[(size_t)token * FEATP_ + 128 + lane] = f2bf(0.0f);
    }
}

// ===================== conv -> featb[64:128] =====================
__global__ __launch_bounds__(256) void k_conv(
    const float* __restrict__ hfpre, const float* __restrict__ conv_w,
    const float* __restrict__ conv_b, __hip_bfloat16* __restrict__ featb) {
    int idx = blockIdx.x * 256 + threadIdx.x;
    int e = idx & 63;
    int bt = idx >> 6;
    int t = bt & (T_ - 1);
    float acc = conv_b[e];
#pragma unroll
    for (int k = 0; k < 4; k++) {
        int tt = t - 3 + k;
        if (tt >= 0) acc += hfpre[(size_t)(bt - 3 + k) * E_ + e] * conv_w[e * 4 + k];
    }
    featb[(size_t)bt * FEATP_ + 64 + e] = f2bf(silu_f(acc));
}

// ===================== scan chain =====================
__global__ __launch_bounds__(256) void k_chunk_ab(
    const float* __restrict__ gates, const float* __restrict__ drive,
    float* __restrict__ chA, float* __restrict__ chB) {
    int gid = blockIdx.x * 256 + threadIdx.x;
    int s = gid & 31;
    int n = (gid >> 5) & (NCH_ - 1);
    int b = gid >> 13;
    int base = (b * T_ + n * CHUNK_) * SS_ + s;
    float suml = 0.f, cum_wb = 0.f, cum_a = 1.f;
    for (int i = 0; i < CHUNK_; i++) {
        float g = gates[base + i * SS_];
        float d = drive[base + i * SS_];
        suml += logf(fmaxf(g, 1e-6f));
        cum_a = expf(suml);
        cum_wb += d / fmaxf(cum_a, 1e-8f);
    }
    chA[gid] = cum_a;
    chB[gid] = cum_a * cum_wb;
}

__global__ void k_chunk_scan(const float* __restrict__ chA, const float* __restrict__ chB,
                             float* __restrict__ chH) {
    int tid = threadIdx.x;     // 256 = B*SS
    int b = tid >> 5, s = tid & 31;
    const float* pA = chA + (size_t)b * NCH_ * SS_ + s;
    const float* pB = chB + (size_t)b * NCH_ * SS_ + s;
    float* pH = chH + (size_t)b * NCH_ * SS_ + s;
    float hc = 0.f;
    for (int n = 0; n < NCH_; n += 8) {
        float a[8], bb[8];
#pragma unroll
        for (int i = 0; i < 8; i++) {
            a[i] = pA[(n + i) * SS_];
            bb[i] = pB[(n + i) * SS_];
        }
#pragma unroll
        for (int i = 0; i < 8; i++) {
            pH[(n + i) * SS_] = hc;
            hc = a[i] * hc + bb[i];
        }
    }
}

__global__ __launch_bounds__(256) void k_states(
    const float* __restrict__ gates, const float* __restrict__ drive,
    const float* __restrict__ chH, __hip_bfloat16* __restrict__ states_bf) {
    int gid = blockIdx.x * 256 + threadIdx.x;
    int s = gid & 31;
    int n = (gid >> 5) & (NCH_ - 1);
    int b = gid >> 13;
    int base = (b * T_ + n * CHUNK_) * SS_ + s;
    float hc = chH[gid];
    float suml = 0.f, cum_wb = 0.f;
    for (int i = 0; i < CHUNK_; i++) {
        float g = gates[base + i * SS_];
        float d = drive[base + i * SS_];
        suml += logf(fmaxf(g, 1e-6f));
        float cum_a = expf(suml);
        cum_wb += d / fmaxf(cum_a, 1e-8f);
        states_bf[base + i * SS_] = f2bf(cum_a * (hc + cum_wb));
    }
}

// ===================== launch =====================
extern "C" void kernel_launch(void* const* d_in, const int* in_sizes, int n_in,
                              void* d_out, int out_size, void* d_ws, size_t ws_size,
                              hipStream_t stream) {
    (void)in_sizes; (void)n_in; (void)out_size; (void)ws_size;
    const int*   chars       = (const int*)  d_in[0];
    const float* emb_byte    = (const float*)d_in[1];
    const float* hash_tables = (const float*)d_in[2];
    const float* Wq          = (const float*)d_in[3];
    const float* bq          = (const float*)d_in[4];
    const float* conv_w      = (const float*)d_in[5];
    const float* conv_b      = (const float*)d_in[6];
    const float* Win         = (const float*)d_in[7];
    const float* b_in        = (const float*)d_in[8];
    const float* Wg          = (const float*)d_in[9];
    const float* bg          = (const float*)d_in[10];
    const float* Wi          = (const float*)d_in[11];
    const float* bi          = (const float*)d_in[12];
    const float* Wo          = (const float*)d_in[13];
    const float* bo          = (const float*)d_in[14];
    const float* ln_g        = (const float*)d_in[15];
    const float* ln_b        = (const float*)d_in[16];
    const float* mlp_w       = (const float*)d_in[17];
    const float* mlp_b       = (const float*)d_in[18];
    const float* Wout        = (const float*)d_in[19];
    const float* bout        = (const float*)d_in[20];
    float* out = (float*)d_out;

    const size_t NTOK = (size_t)B_ * T_;  // 65536
    char* p = (char*)d_ws;
    auto alloc = [&](size_t bytes) { void* r = (void*)p; p += (bytes + 255) & ~(size_t)255; return r; };
    __hip_bfloat16* featb = (__hip_bfloat16*)alloc(NTOK * FEATP_ * 2);
    float*          hfpre = (float*)alloc(NTOK * E_ * 4);
    __hip_bfloat16* hbA   = (__hip_bfloat16*)alloc(NTOK * H_ * 2);
    __hip_bfloat16* hbB   = (__hip_bfloat16*)alloc(NTOK * H_ * 2);
    float*          gates = (float*)alloc(NTOK * SS_ * 4);
    float*          drive = (float*)alloc(NTOK * SS_ * 4);
    __hip_bfloat16* states_bf = (__hip_bfloat16*)alloc(NTOK * SS_ * 2);
    float*          chA   = (float*)alloc((size_t)B_ * NCH_ * SS_ * 4);
    float*          chB   = (float*)alloc((size_t)B_ * NCH_ * SS_ * 4);
    float*          chH   = (float*)alloc((size_t)B_ * NCH_ * SS_ * 4);
    __hip_bfloat16* Wt_mlp= (__hip_bfloat16*)alloc(3 * 512 * 512 * 2);
    __hip_bfloat16* Wt_out= (__hip_bfloat16*)alloc(256 * 512 * 2);
    __hip_bfloat16* Wt_win= (__hip_bfloat16*)alloc(512 * FEATP_ * 2);
    __hip_bfloat16* Wt_gd = (__hip_bfloat16*)alloc(64 * 512 * 2);
    __hip_bfloat16* Wt_wo = (__hip_bfloat16*)alloc(512 * SS_ * 2);
    float*          Qtab  = (float*)alloc(256 * 64 * 4);
    __hip_bfloat16* Wt_wo2= (__hip_bfloat16*)alloc(32 * 512 * 2);

    k_prep_w<<<4288, 256, 0, stream>>>(mlp_w, Wout, Win, Wg, Wi, Wo, Wq, bq, emb_byte,
                                       Wt_mlp, Wt_out, Wt_win, Wt_gd, Wt_wo, Qtab, Wt_wo2);
    k_token_feats<<<NTOK / 4, 256, 0, stream>>>(chars, emb_byte, hash_tables, Qtab, featb, hfpre);
    k_conv<<<NTOK * E_ / 256, 256, 0, stream>>>(hfpre, conv_w, conv_b, featb);
    k_win256<<<512, 512, 0, stream>>>(featb, Wt_win, b_in, hbA);
    k_gates_mfma<<<NTOK / 256, 256, 0, stream>>>(hbA, Wt_gd, bg, bi, gates, drive);
    k_chunk_ab<<<B_ * NCH_ * SS_ / 256, 256, 0, stream>>>(gates, drive, chA, chB);
    k_chunk_scan<<<1, 256, 0, stream>>>(chA, chB, chH);
    k_states<<<B_ * NCH_ * SS_ / 256, 256, 0, stream>>>(gates, drive, chH, states_bf);
    k_wln<<<NTOK / 64, 512, 0, stream>>>(states_bf, Wt_wo2, bo, hbA, ln_g, ln_b, hbB);
    k_mlp256<<<512, 512, 0, stream>>>(hbB, Wt_mlp, mlp_b, hbA);
    k_mlp256<<<512, 512, 0, stream>>>(hbA, Wt_mlp + 262144, mlp_b + 512, hbB);
    k_mlp256<<<512, 512, 0, stream>>>(hbB, Wt_mlp + 524288, mlp_b + 1024, hbA);
    k_out256<<<256, 512, 0, stream>>>(hbA, Wt_out, bout, out);
}

// Round 10
// 528.561 us; speedup vs baseline: 2.0742x; 2.0742x over previous
//
#include <hip/hip_runtime.h>
#include <hip/hip_bf16.h>
#include <math.h>

#define B_ 8
#define T_ 8192
#define V_ 256
#define EB_ 64
#define E_ 64
#define H_ 512
#define SS_ 32
#define FEATP_ 192   // padded feature dim (real 132, zero-padded to 192 = 3*64 for BK=64 core)
#define NCH_ 256
#define CHUNK_ 32

typedef __attribute__((ext_vector_type(8))) short bf8;     // 8 bf16 = 4 VGPRs (MFMA A/B frag)
typedef __attribute__((ext_vector_type(16))) float accv;   // MFMA 32x32 C/D frag

#define AS1(p) (__attribute__((address_space(1))) void*)(void*)(p)
#define AS3(p) (__attribute__((address_space(3))) void*)(void*)(p)

__device__ __forceinline__ float silu_f(float x) { return x / (1.0f + expf(-x)); }
__device__ __forceinline__ float sigm_f(float x) { return 1.0f / (1.0f + expf(-x)); }
__device__ __forceinline__ float bf2f(__hip_bfloat16 v) { return __bfloat162float(v); }
__device__ __forceinline__ __hip_bfloat16 f2bf(float v) { return __float2bfloat16(v); }
__device__ __forceinline__ float us2f(ushort u) {
    union { float f; unsigned int u32; } c; c.u32 = ((unsigned int)u) << 16; return c.f;
}
__device__ __forceinline__ ushort f2us(float v) {
    __hip_bfloat16 t = __float2bfloat16(v);
    return *reinterpret_cast<ushort*>(&t);
}
__device__ __forceinline__ float rdlane(float v, int l) {
    return __int_as_float(__builtin_amdgcn_readlane(__float_as_int(v), l));
}

#define CD_ROW(r, lane) (((r) & 3) + 8 * ((r) >> 2) + 4 * ((lane) >> 5))

// bijective XCD-chunk swizzle (nwg % 8 == 0): neighbor wgids land on same XCD L2
__device__ __forceinline__ int xcd_swz(int bid, int nwg) {
    return (bid & 7) * (nwg >> 3) + (bid >> 3);
}

// ===================== 256x256 MFMA core (R5-verified, 73us/mlp) =====================
template <int KD>
__device__ __forceinline__ void mm256(const ushort* __restrict__ Ab,
                                      const ushort* __restrict__ Bb,
                                      int m0, int n0, accv (&acc)[4][2]) {
    constexpr int NT = KD / 64;
    __shared__ __align__(1024) ushort lA[33280];   // 66560 B: 2 slots x 32 grp x 520us
    __shared__ __align__(1024) ushort lB[33280];
    const int tid  = threadIdx.x;
    const int lane = tid & 63;
    const int w    = tid >> 6;
    const int wm   = w >> 2, wn = w & 3;
    const int l31  = lane & 31, lh = lane >> 5;

    const int srow = lane >> 3;                          // 0..7
    const int scg  = (lane & 7) ^ ((srow & 1) << 2);     // 64B-half swap only
    const ushort* gA = Ab + (size_t)(m0 + w * 32 + srow) * KD + scg * 8;
    const ushort* gB = Bb + (size_t)(n0 + w * 32 + srow) * KD + scg * 8;
    const int dgrp = w * 4;

    const int rbase = (l31 >> 3) * 520 + (l31 & 7) * 64;
    int oK[4];
#pragma unroll
    for (int ks = 0; ks < 4; ks++) oK[ks] = (((ks * 2 + lh) ^ ((l31 & 1) << 2)) << 3);
    const int aoff = wm * 8320 + rbase;
    const int boff = wn * 4160 + rbase;

#define STG8(slot, kt)                                                                             \
    do {                                                                                           \
        __builtin_amdgcn_global_load_lds(AS1(gA + (kt)),                                           \
                                         AS3(&lA[(slot) * 16640 + (dgrp + 0) * 520]), 16, 0, 0);   \
        __builtin_amdgcn_global_load_lds(AS1(gB + (kt)),                                           \
                                         AS3(&lB[(slot) * 16640 + (dgrp + 0) * 520]), 16, 0, 0);   \
        __builtin_amdgcn_global_load_lds(AS1(gA + (size_t)8 * KD + (kt)),                          \
                                         AS3(&lA[(slot) * 16640 + (dgrp + 1) * 520]), 16, 0, 0);   \
        __builtin_amdgcn_global_load_lds(AS1(gB + (size_t)8 * KD + (kt)),                          \
                                         AS3(&lB[(slot) * 16640 + (dgrp + 1) * 520]), 16, 0, 0);   \
        __builtin_amdgcn_global_load_lds(AS1(gA + (size_t)16 * KD + (kt)),                         \
                                         AS3(&lA[(slot) * 16640 + (dgrp + 2) * 520]), 16, 0, 0);   \
        __builtin_amdgcn_global_load_lds(AS1(gB + (size_t)16 * KD + (kt)),                         \
                                         AS3(&lB[(slot) * 16640 + (dgrp + 2) * 520]), 16, 0, 0);   \
        __builtin_amdgcn_global_load_lds(AS1(gA + (size_t)24 * KD + (kt)),                         \
                                         AS3(&lA[(slot) * 16640 + (dgrp + 3) * 520]), 16, 0, 0);   \
        __builtin_amdgcn_global_load_lds(AS1(gB + (size_t)24 * KD + (kt)),                         \
                                         AS3(&lB[(slot) * 16640 + (dgrp + 3) * 520]), 16, 0, 0);   \
    } while (0)

#define PH(slot, ks)                                                                               \
    do {                                                                                           \
        const ushort* pa = &lA[(slot) * 16640 + aoff + oK[ks]];                                    \
        const ushort* pb = &lB[(slot) * 16640 + boff + oK[ks]];                                    \
        bf8 b0v = *(const bf8*)(pb);                                                               \
        bf8 b1v = *(const bf8*)(pb + 2080);                                                        \
        bf8 a0v = *(const bf8*)(pa);                                                               \
        bf8 a1v = *(const bf8*)(pa + 2080);                                                        \
        bf8 a2v = *(const bf8*)(pa + 4160);                                                        \
        bf8 a3v = *(const bf8*)(pa + 6240);                                                        \
        acc[0][0] = __builtin_amdgcn_mfma_f32_32x32x16_bf16(a0v, b0v, acc[0][0], 0, 0, 0);         \
        acc[0][1] = __builtin_amdgcn_mfma_f32_32x32x16_bf16(a0v, b1v, acc[0][1], 0, 0, 0);         \
        acc[1][0] = __builtin_amdgcn_mfma_f32_32x32x16_bf16(a1v, b0v, acc[1][0], 0, 0, 0);         \
        acc[1][1] = __builtin_amdgcn_mfma_f32_32x32x16_bf16(a1v, b1v, acc[1][1], 0, 0, 0);         \
        acc[2][0] = __builtin_amdgcn_mfma_f32_32x32x16_bf16(a2v, b0v, acc[2][0], 0, 0, 0);         \
        acc[2][1] = __builtin_amdgcn_mfma_f32_32x32x16_bf16(a2v, b1v, acc[2][1], 0, 0, 0);         \
        acc[3][0] = __builtin_amdgcn_mfma_f32_32x32x16_bf16(a3v, b0v, acc[3][0], 0, 0, 0);         \
        acc[3][1] = __builtin_amdgcn_mfma_f32_32x32x16_bf16(a3v, b1v, acc[3][1], 0, 0, 0);         \
    } while (0)

    STG8(0, 0);
#pragma unroll
    for (int t = 0; t < NT - 1; ++t) {
        const int slot = t & 1;
        STG8(slot ^ 1, (t + 1) * 64);
        asm volatile("s_waitcnt vmcnt(8)" ::: "memory");
        __builtin_amdgcn_s_barrier();
        __builtin_amdgcn_sched_barrier(0);
        __builtin_amdgcn_s_setprio(1);
        PH(slot, 0); PH(slot, 1); PH(slot, 2); PH(slot, 3);
        __builtin_amdgcn_s_setprio(0);
        __builtin_amdgcn_s_barrier();
    }
    asm volatile("s_waitcnt vmcnt(0)" ::: "memory");
    __builtin_amdgcn_s_barrier();
    __builtin_amdgcn_sched_barrier(0);
    {
        const int ls = (NT - 1) & 1;
        __builtin_amdgcn_s_setprio(1);
        PH(ls, 0); PH(ls, 1); PH(ls, 2); PH(ls, 3);
        __builtin_amdgcn_s_setprio(0);
    }
#undef STG8
#undef PH
}

__device__ __forceinline__ void zero_acc8(accv (&acc)[4][2]) {
#pragma unroll
    for (int i = 0; i < 4; i++)
#pragma unroll
        for (int j = 0; j < 2; j++)
#pragma unroll
            for (int r = 0; r < 16; r++) acc[i][j][r] = 0.0f;
}

// ---------------- MLP residual block: hout = hin + silu(hin @ W + b)
__global__ __launch_bounds__(512, 2) void k_mlp256(const __hip_bfloat16* __restrict__ hin,
                                                   const __hip_bfloat16* __restrict__ Wt,
                                                   const float* __restrict__ bias,
                                                   __hip_bfloat16* __restrict__ hout) {
    accv acc[4][2];
    zero_acc8(acc);
    int wg = xcd_swz(blockIdx.x, 512);
    int m0 = (wg >> 1) * 256, n0 = (wg & 1) * 256;
    int lane = threadIdx.x & 63, w = threadIdx.x >> 6, wm = w >> 2, wn = w & 3;
    mm256<H_>((const ushort*)hin, (const ushort*)Wt, m0, n0, acc);
#pragma unroll
    for (int fr = 0; fr < 4; fr++)
#pragma unroll
        for (int fc = 0; fc < 2; fc++) {
            int col = n0 + 64 * wn + 32 * fc + (lane & 31);
            float bv = bias[col];
#pragma unroll
            for (int r = 0; r < 16; r++) {
                int row = m0 + 128 * wm + 32 * fr + CD_ROW(r, lane);
                float v = acc[fr][fc][r] + bv;
                float res = bf2f(hin[(size_t)row * H_ + col]);
                hout[(size_t)row * H_ + col] = f2bf(res + silu_f(v));
            }
        }
}

// ---------------- Win: hb = bf16(silu(featb @ Win + b_in)), KD=192 (zero-padded)
__global__ __launch_bounds__(512, 2) void k_win256(const __hip_bfloat16* __restrict__ featb,
                                                   const __hip_bfloat16* __restrict__ Wt,
                                                   const float* __restrict__ bias,
                                                   __hip_bfloat16* __restrict__ hb) {
    accv acc[4][2];
    zero_acc8(acc);
    int wg = xcd_swz(blockIdx.x, 512);
    int m0 = (wg >> 1) * 256, n0 = (wg & 1) * 256;
    int lane = threadIdx.x & 63, w = threadIdx.x >> 6, wm = w >> 2, wn = w & 3;
    mm256<FEATP_>((const ushort*)featb, (const ushort*)Wt, m0, n0, acc);
#pragma unroll
    for (int fr = 0; fr < 4; fr++)
#pragma unroll
        for (int fc = 0; fc < 2; fc++) {
            int col = n0 + 64 * wn + 32 * fc + (lane & 31);
            float bv = bias[col];
#pragma unroll
            for (int r = 0; r < 16; r++) {
                int row = m0 + 128 * wm + 32 * fr + CD_ROW(r, lane);
                hb[(size_t)row * H_ + col] = f2bf(silu_f(acc[fr][fc][r] + bv));
            }
        }
}

// ---------------- Out: out = hb @ Wout + bout (fp32 out, N=256 single n-block)
__global__ __launch_bounds__(512, 2) void k_out256(const __hip_bfloat16* __restrict__ hb,
                                                   const __hip_bfloat16* __restrict__ Wt,
                                                   const float* __restrict__ bout,
                                                   float* __restrict__ out) {
    accv acc[4][2];
    zero_acc8(acc);
    int wg = xcd_swz(blockIdx.x, 256);
    int m0 = wg * 256;
    int lane = threadIdx.x & 63, w = threadIdx.x >> 6, wm = w >> 2, wn = w & 3;
    mm256<H_>((const ushort*)hb, (const ushort*)Wt, m0, 0, acc);
#pragma unroll
    for (int fr = 0; fr < 4; fr++)
#pragma unroll
        for (int fc = 0; fc < 2; fc++) {
            int col = 64 * wn + 32 * fc + (lane & 31);
            float bv = bout[col];
#pragma unroll
            for (int r = 0; r < 16; r++) {
                int row = m0 + 128 * wm + 32 * fr + CD_ROW(r, lane);
                out[(size_t)row * V_ + col] = acc[fr][fc][r] + bv;
            }
        }
}

// ===================== FUSED womm+LN (VALU, no tmp round-trip) =====================
// h_out[tok] = LN( h_in[tok] + states[tok] @ Wo + bo )
// R9 lesson: the spill was NOT the lambda — the fully-unrolled k-loop let the
// scheduler hoist all 32 ds_read_b128 (wu) -> 128 VGPRs of W live at once ->
// allocator (capped at 128 on 512-thr blocks) spilled the accumulators.
// Fix: (1) sched_barrier(0) per k-iteration fences the hoist (<=2 wu live);
// (2) 256-thread blocks (every 512-thr kernel here was VGPR-capped at 128).
#define LN_STORE(ax, tok)                                                                   \
    do {                                                                                    \
        float sm = ax[0] + ax[1] + ax[2] + ax[3] + ax[4] + ax[5] + ax[6] + ax[7];           \
        float sq = ax[0]*ax[0] + ax[1]*ax[1] + ax[2]*ax[2] + ax[3]*ax[3]                    \
                 + ax[4]*ax[4] + ax[5]*ax[5] + ax[6]*ax[6] + ax[7]*ax[7];                   \
        sm += __shfl_xor(sm, 32, 64); sq += __shfl_xor(sq, 32, 64);                         \
        sm += __shfl_xor(sm, 16, 64); sq += __shfl_xor(sq, 16, 64);                         \
        sm += __shfl_xor(sm, 8, 64);  sq += __shfl_xor(sq, 8, 64);                          \
        sm += __shfl_xor(sm, 4, 64);  sq += __shfl_xor(sq, 4, 64);                          \
        sm += __shfl_xor(sm, 2, 64);  sq += __shfl_xor(sq, 2, 64);                          \
        sm += __shfl_xor(sm, 1, 64);  sq += __shfl_xor(sq, 1, 64);                          \
        float mu = sm * (1.0f / 512.0f);                                                    \
        float var = sq * (1.0f / 512.0f) - mu * mu;                                         \
        float rstd = rsqrtf(fmaxf(var, 0.0f) + 1e-5f);                                      \
        bf8 o;                                                                              \
        o[0] = (short)f2us((ax[0] - mu) * rstd * gg0 + bb0);                                \
        o[1] = (short)f2us((ax[1] - mu) * rstd * gg1 + bb1);                                \
        o[2] = (short)f2us((ax[2] - mu) * rstd * gg2 + bb2);                                \
        o[3] = (short)f2us((ax[3] - mu) * rstd * gg3 + bb3);                                \
        o[4] = (short)f2us((ax[4] - mu) * rstd * gg4 + bb4);                                \
        o[5] = (short)f2us((ax[5] - mu) * rstd * gg5 + bb5);                                \
        o[6] = (short)f2us((ax[6] - mu) * rstd * gg6 + bb6);                                \
        o[7] = (short)f2us((ax[7] - mu) * rstd * gg7 + bb7);                                \
        *(bf8*)(Ob + (size_t)(tok) * 512 + lane * 8) = o;                                   \
    } while (0)

__global__ __launch_bounds__(256) void k_wln(
    const __hip_bfloat16* __restrict__ states_bf,
    const __hip_bfloat16* __restrict__ Wo2,       // [32][512] bf16
    const float* __restrict__ bo,
    const __hip_bfloat16* __restrict__ h_in,
    const float* __restrict__ ln_g,
    const float* __restrict__ ln_b,
    __hip_bfloat16* __restrict__ h_out) {
    __shared__ __align__(1024) ushort lW[16384];   // 32 KiB
    const int tid = threadIdx.x, lane = tid & 63, w = tid >> 6;   // 4 waves

    // stage Wo2 -> LDS: wave w covers 8 KB, 8 instrs of 1 KB
    {
        const ushort* srcw = (const ushort*)Wo2 + w * 4096 + lane * 8;   // per-lane src
        ushort* dstw = &lW[w * 4096];                                     // wave-uniform dst
#pragma unroll
        for (int i = 0; i < 8; ++i)
            __builtin_amdgcn_global_load_lds(AS1(srcw + i * 512), AS3(dstw + i * 512), 16, 0, 0);
    }

    // per-lane constants (cols lane*8 .. lane*8+7) — all NAMED scalars
    float4 g0 = *(const float4*)(ln_g + lane * 8);
    float4 g1 = *(const float4*)(ln_g + lane * 8 + 4);
    float4 lb0 = *(const float4*)(ln_b + lane * 8);
    float4 lb1 = *(const float4*)(ln_b + lane * 8 + 4);
    float4 bo0 = *(const float4*)(bo + lane * 8);
    float4 bo1 = *(const float4*)(bo + lane * 8 + 4);
    float gg0 = g0.x, gg1 = g0.y, gg2 = g0.z, gg3 = g0.w;
    float gg4 = g1.x, gg5 = g1.y, gg6 = g1.z, gg7 = g1.w;
    float bb0 = lb0.x, bb1 = lb0.y, bb2 = lb0.z, bb3 = lb0.w;
    float bb4 = lb1.x, bb5 = lb1.y, bb6 = lb1.z, bb7 = lb1.w;
    float bv0 = bo0.x, bv1 = bo0.y, bv2 = bo0.z, bv3 = bo0.w;
    float bv4 = bo1.x, bv5 = bo1.y, bv6 = bo1.z, bv7 = bo1.w;

    asm volatile("s_waitcnt vmcnt(0)" ::: "memory");
    __syncthreads();

    const ushort* Sb = (const ushort*)states_bf;
    const ushort* Hb = (const ushort*)h_in;
    ushort* Ob = (ushort*)h_out;

    // block covers 32 tokens; wave w owns tokens [bid*32 + w*8, +8), 2 per pass
    for (int pass = 0; pass < 4; ++pass) {
        const int tok0 = blockIdx.x * 32 + w * 8 + pass * 2;
        // states rows: 2 tokens x 32 bf16; lanes 0-31 tok0, 32-63 tok1
        float sv = us2f(Sb[(size_t)tok0 * 32 + lane]);
        // h rows + bias -> fp32 acc
        const ushort* h0 = Hb + (size_t)tok0 * 512 + lane * 8;
        float a0[8], a1[8];
        {
            uint4 u0 = *(const uint4*)(h0);
            uint4 u1 = *(const uint4*)(h0 + 512);
            a0[0] = __uint_as_float(u0.x << 16) + bv0;
            a0[1] = __uint_as_float(u0.x & 0xffff0000u) + bv1;
            a0[2] = __uint_as_float(u0.y << 16) + bv2;
            a0[3] = __uint_as_float(u0.y & 0xffff0000u) + bv3;
            a0[4] = __uint_as_float(u0.z << 16) + bv4;
            a0[5] = __uint_as_float(u0.z & 0xffff0000u) + bv5;
            a0[6] = __uint_as_float(u0.w << 16) + bv6;
            a0[7] = __uint_as_float(u0.w & 0xffff0000u) + bv7;
            a1[0] = __uint_as_float(u1.x << 16) + bv0;
            a1[1] = __uint_as_float(u1.x & 0xffff0000u) + bv1;
            a1[2] = __uint_as_float(u1.y << 16) + bv2;
            a1[3] = __uint_as_float(u1.y & 0xffff0000u) + bv3;
            a1[4] = __uint_as_float(u1.z << 16) + bv4;
            a1[5] = __uint_as_float(u1.z & 0xffff0000u) + bv5;
            a1[6] = __uint_as_float(u1.w << 16) + bv6;
            a1[7] = __uint_as_float(u1.w & 0xffff0000u) + bv7;
        }
        // womm: acc += states @ Wo (lane-broadcast FMA).
        // sched_barrier(0) per iteration: fence ds_read hoisting (R9 spill cause).
#pragma unroll
        for (int k = 0; k < 32; ++k) {
            uint4 wu = *(const uint4*)&lW[k * 512 + lane * 8];
            float s0k = rdlane(sv, k);
            float s1k = rdlane(sv, 32 + k);
            float wf0 = __uint_as_float(wu.x << 16);
            float wf1 = __uint_as_float(wu.x & 0xffff0000u);
            float wf2 = __uint_as_float(wu.y << 16);
            float wf3 = __uint_as_float(wu.y & 0xffff0000u);
            float wf4 = __uint_as_float(wu.z << 16);
            float wf5 = __uint_as_float(wu.z & 0xffff0000u);
            float wf6 = __uint_as_float(wu.w << 16);
            float wf7 = __uint_as_float(wu.w & 0xffff0000u);
            a0[0] = fmaf(s0k, wf0, a0[0]); a1[0] = fmaf(s1k, wf0, a1[0]);
            a0[1] = fmaf(s0k, wf1, a0[1]); a1[1] = fmaf(s1k, wf1, a1[1]);
            a0[2] = fmaf(s0k, wf2, a0[2]); a1[2] = fmaf(s1k, wf2, a1[2]);
            a0[3] = fmaf(s0k, wf3, a0[3]); a1[3] = fmaf(s1k, wf3, a1[3]);
            a0[4] = fmaf(s0k, wf4, a0[4]); a1[4] = fmaf(s1k, wf4, a1[4]);
            a0[5] = fmaf(s0k, wf5, a0[5]); a1[5] = fmaf(s1k, wf5, a1[5]);
            a0[6] = fmaf(s0k, wf6, a0[6]); a1[6] = fmaf(s1k, wf6, a1[6]);
            a0[7] = fmaf(s0k, wf7, a0[7]); a1[7] = fmaf(s1k, wf7, a1[7]);
            __builtin_amdgcn_sched_barrier(0);
        }
        // LN per token (full 512-col row spans the wave) + store
        LN_STORE(a0, tok0);
        LN_STORE(a1, tok0 + 1);
    }
}

// ---------------- gates/drive: [g|i] = hb @ [Wg|Wi]; tile 256x64, K=512
__global__ __launch_bounds__(256) void k_gates_mfma(const __hip_bfloat16* __restrict__ hb,
                                                    const __hip_bfloat16* __restrict__ Wt_gd,
                                                    const float* __restrict__ bg,
                                                    const float* __restrict__ bi,
                                                    float* __restrict__ gates,
                                                    float* __restrict__ drive) {
    __shared__ __align__(16) ushort lA[256 * 32];
    __shared__ __align__(16) ushort lB[64 * 32];
    int tid = threadIdx.x, lane = tid & 63, w = tid >> 6;
    int m0 = blockIdx.x * 256;
    accv acc[2][2];
#pragma unroll
    for (int i = 0; i < 2; i++)
#pragma unroll
        for (int j = 0; j < 2; j++)
#pragma unroll
            for (int r = 0; r < 16; r++) acc[i][j][r] = 0.0f;
    const ushort* Ab = (const ushort*)hb;
    const ushort* Bb = (const ushort*)Wt_gd;
    const ushort* pa = &lA[(64 * w + (lane & 31)) * 32 + (lane >> 5) * 8];
    const ushort* pb = &lB[((lane & 31)) * 32 + (lane >> 5) * 8];
    int cb = w * 64 + lane;
    const ushort* gB = Bb + (size_t)(cb >> 2) * H_ + (cb & 3) * 8;
    for (int kt = 0; kt < H_; kt += 32) {
#pragma unroll
        for (int j = 0; j < 4; j++) {
            int c = w * 256 + j * 64 + lane;
            __builtin_amdgcn_global_load_lds(
                AS1(Ab + (size_t)(m0 + (c >> 2)) * H_ + (c & 3) * 8 + kt),
                AS3(&lA[(w * 256 + j * 64) * 8]), 16, 0, 0);
        }
        __builtin_amdgcn_global_load_lds(AS1(gB + kt), AS3(&lB[(w * 64) * 8]), 16, 0, 0);
        __syncthreads();
#pragma unroll
        for (int ks = 0; ks < 2; ks++) {
            bf8 a0 = *(const bf8*)(pa + ks * 16);
            bf8 a1 = *(const bf8*)(pa + 32 * 32 + ks * 16);
            bf8 b0 = *(const bf8*)(pb + ks * 16);
            bf8 b1 = *(const bf8*)(pb + 32 * 32 + ks * 16);
            acc[0][0] = __builtin_amdgcn_mfma_f32_32x32x16_bf16(a0, b0, acc[0][0], 0, 0, 0);
            acc[0][1] = __builtin_amdgcn_mfma_f32_32x32x16_bf16(a0, b1, acc[0][1], 0, 0, 0);
            acc[1][0] = __builtin_amdgcn_mfma_f32_32x32x16_bf16(a1, b0, acc[1][0], 0, 0, 0);
            acc[1][1] = __builtin_amdgcn_mfma_f32_32x32x16_bf16(a1, b1, acc[1][1], 0, 0, 0);
        }
        __syncthreads();
    }
    int c = lane & 31;
    float bgv = bg[c], biv = bi[c];
#pragma unroll
    for (int i = 0; i < 2; i++)
#pragma unroll
        for (int r = 0; r < 16; r++) {
            int row = m0 + 64 * w + 32 * i + CD_ROW(r, lane);
            float g = sigm_f(acc[i][0][r] + bgv);
            float d = (1.0f - g) * (acc[i][1][r] + biv);
            gates[(size_t)row * SS_ + c] = g;
            drive[(size_t)row * SS_ + c] = d;
        }
}

// ===================== weight prep: bf16 + transpose + Qtab =====================
// regions: mlp[0,786432) out[786432,917504) win[917504,1015808) gd[1015808,1048576)
//          wo[1048576,1064960) qtab[1064960,1081344) wo2[1081344,1097728)
__global__ __launch_bounds__(256) void k_prep_w(const float* __restrict__ mlp_w,
                                                const float* __restrict__ Wout,
                                                const float* __restrict__ Win,
                                                const float* __restrict__ Wg,
                                                const float* __restrict__ Wi,
                                                const float* __restrict__ Wo,
                                                const float* __restrict__ Wq,
                                                const float* __restrict__ bq,
                                                const float* __restrict__ emb_byte,
                                                __hip_bfloat16* __restrict__ Wt_mlp,
                                                __hip_bfloat16* __restrict__ Wt_out,
                                                __hip_bfloat16* __restrict__ Wt_win,
                                                __hip_bfloat16* __restrict__ Wt_gd,
                                                __hip_bfloat16* __restrict__ Wt_wo,
                                                float* __restrict__ Qtab,
                                                __hip_bfloat16* __restrict__ Wt_wo2) {
    int idx = blockIdx.x * 256 + threadIdx.x;
    if (idx < 786432) {
        int l = idx >> 18, rem = idx & 262143;
        int n = rem >> 9, k = rem & 511;
        Wt_mlp[idx] = f2bf(mlp_w[l * 262144 + k * 512 + n]);
    } else if (idx < 917504) {
        int rem = idx - 786432;
        int n = rem >> 9, k = rem & 511;
        Wt_out[rem] = f2bf(Wout[k * 256 + n]);
    } else if (idx < 1015808) {
        int rem = idx - 917504;
        int n = rem / FEATP_, k = rem % FEATP_;
        Wt_win[rem] = f2bf(k < 132 ? Win[k * 512 + n] : 0.0f);
    } else if (idx < 1048576) {
        int rem = idx - 1015808;
        int n = rem >> 9, k = rem & 511;
        Wt_gd[rem] = f2bf(n < 32 ? Wg[k * 32 + n] : Wi[k * 32 + (n - 32)]);
    } else if (idx < 1064960) {
        int rem = idx - 1048576;
        int n = rem >> 5, k = rem & 31;
        Wt_wo[rem] = f2bf(Wo[k * H_ + n]);
    } else if (idx < 1081344) {
        int rem = idx - 1064960;
        int c = rem >> 6, e = rem & 63;
        float a = bq[e];
#pragma unroll 8
        for (int k = 0; k < 64; k++) a += emb_byte[c * 64 + k] * Wq[k * 64 + e];
        Qtab[rem] = a * 0.125f;   // fold 1/sqrt(E) score scale
    } else if (idx < 1097728) {
        int rem = idx - 1081344;           // [k][c] natural layout for k_wln
        Wt_wo2[rem] = f2bf(Wo[rem]);       // Wo is (32,512) row-major already
    }
}

// ===================== token features (Qtab-based, no matvec) =====================
__global__ __launch_bounds__(256) void k_token_feats(
    const int* __restrict__ chars, const float* __restrict__ emb_byte,
    const float* __restrict__ hash_tables, const float* __restrict__ Qtab,
    __hip_bfloat16* __restrict__ featb, float* __restrict__ hfpre) {
    int wave = threadIdx.x >> 6, lane = threadIdx.x & 63;
    int token = blockIdx.x * 4 + wave;
    int t = token & (T_ - 1);
    int b = token >> 13;
    const int* crow = chars + b * T_;
    int cv[16];
#pragma unroll
    for (int j = 0; j < 16; j++) cv[j] = (t >= j) ? crow[t - j] : 0;
    int acc = 0;
    int hidx[4];
#pragma unroll
    for (int j = 0; j < 16; j++) {
        acc += cv[j] * (1 + 256 * j);
        if (j == 1) hidx[0] = acc & 4095;
        if (j == 3) hidx[1] = acc & 4095;
        if (j == 7) hidx[2] = acc & 4095;
        if (j == 15) hidx[3] = acc & 4095;
    }
    int c0 = cv[0];
    float be = emb_byte[c0 * EB_ + lane];
    float q = Qtab[c0 * 64 + lane];
    float se[4];
#pragma unroll
    for (int s = 0; s < 4; s++) se[s] = hash_tables[(s * 4096 + hidx[s]) * E_ + lane];
    float sc[4];
#pragma unroll
    for (int s = 0; s < 4; s++) {
        float v = q * se[s];
#pragma unroll
        for (int off = 32; off; off >>= 1) v += __shfl_xor(v, off, 64);
        sc[s] = v;
    }
    float mx = fmaxf(fmaxf(sc[0], sc[1]), fmaxf(sc[2], sc[3]));
    float w0 = expf(sc[0] - mx), w1 = expf(sc[1] - mx), w2 = expf(sc[2] - mx), w3 = expf(sc[3] - mx);
    float inv = 1.0f / (w0 + w1 + w2 + w3);
    float hf = (w0 * se[0] + w1 * se[1] + w2 * se[2] + w3 * se[3]) * inv;
    featb[(size_t)token * FEATP_ + lane] = f2bf(be);
    hfpre[(size_t)token * E_ + lane] = hf;
    if (lane < 32) {
        float m = 0.0f;
        if (lane < 4) {
            int k = 1 << lane;
            m = (t >= k && c0 == cv[k]) ? 1.0f : 0.0f;
        }
        featb[(size_t)token * FEATP_ + 128 + lane] = f2bf(m);
    } else {
        featb[(size_t)token * FEATP_ + 128 + lane] = f2bf(0.0f);
    }
}

// ===================== conv -> featb[64:128] =====================
__global__ __launch_bounds__(256) void k_conv(
    const float* __restrict__ hfpre, const float* __restrict__ conv_w,
    const float* __restrict__ conv_b, __hip_bfloat16* __restrict__ featb) {
    int idx = blockIdx.x * 256 + threadIdx.x;
    int e = idx & 63;
    int bt = idx >> 6;
    int t = bt & (T_ - 1);
    float acc = conv_b[e];
#pragma unroll
    for (int k = 0; k < 4; k++) {
        int tt = t - 3 + k;
        if (tt >= 0) acc += hfpre[(size_t)(bt - 3 + k) * E_ + e] * conv_w[e * 4 + k];
    }
    featb[(size_t)bt * FEATP_ + 64 + e] = f2bf(silu_f(acc));
}

// ===================== scan chain =====================
__global__ __launch_bounds__(256) void k_chunk_ab(
    const float* __restrict__ gates, const float* __restrict__ drive,
    float* __restrict__ chA, float* __restrict__ chB) {
    int gid = blockIdx.x * 256 + threadIdx.x;
    int s = gid & 31;
    int n = (gid >> 5) & (NCH_ - 1);
    int b = gid >> 13;
    int base = (b * T_ + n * CHUNK_) * SS_ + s;
    float suml = 0.f, cum_wb = 0.f, cum_a = 1.f;
    for (int i = 0; i < CHUNK_; i++) {
        float g = gates[base + i * SS_];
        float d = drive[base + i * SS_];
        suml += logf(fmaxf(g, 1e-6f));
        cum_a = expf(suml);
        cum_wb += d / fmaxf(cum_a, 1e-8f);
    }
    chA[gid] = cum_a;
    chB[gid] = cum_a * cum_wb;
}

__global__ void k_chunk_scan(const float* __restrict__ chA, const float* __restrict__ chB,
                             float* __restrict__ chH) {
    int tid = threadIdx.x;     // 256 = B*SS
    int b = tid >> 5, s = tid & 31;
    const float* pA = chA + (size_t)b * NCH_ * SS_ + s;
    const float* pB = chB + (size_t)b * NCH_ * SS_ + s;
    float* pH = chH + (size_t)b * NCH_ * SS_ + s;
    float hc = 0.f;
    for (int n = 0; n < NCH_; n += 8) {
        float a[8], bb[8];
#pragma unroll
        for (int i = 0; i < 8; i++) {
            a[i] = pA[(n + i) * SS_];
            bb[i] = pB[(n + i) * SS_];
        }
#pragma unroll
        for (int i = 0; i < 8; i++) {
            pH[(n + i) * SS_] = hc;
            hc = a[i] * hc + bb[i];
        }
    }
}

__global__ __launch_bounds__(256) void k_states(
    const float* __restrict__ gates, const float* __restrict__ drive,
    const float* __restrict__ chH, __hip_bfloat16* __restrict__ states_bf) {
    int gid = blockIdx.x * 256 + threadIdx.x;
    int s = gid & 31;
    int n = (gid >> 5) & (NCH_ - 1);
    int b = gid >> 13;
    int base = (b * T_ + n * CHUNK_) * SS_ + s;
    float hc = chH[gid];
    float suml = 0.f, cum_wb = 0.f;
    for (int i = 0; i < CHUNK_; i++) {
        float g = gates[base + i * SS_];
        float d = drive[base + i * SS_];
        suml += logf(fmaxf(g, 1e-6f));
        float cum_a = expf(suml);
        cum_wb += d / fmaxf(cum_a, 1e-8f);
        states_bf[base + i * SS_] = f2bf(cum_a * (hc + cum_wb));
    }
}

// ===================== launch =====================
extern "C" void kernel_launch(void* const* d_in, const int* in_sizes, int n_in,
                              void* d_out, int out_size, void* d_ws, size_t ws_size,
                              hipStream_t stream) {
    (void)in_sizes; (void)n_in; (void)out_size; (void)ws_size;
    const int*   chars       = (const int*)  d_in[0];
    const float* emb_byte    = (const float*)d_in[1];
    const float* hash_tables = (const float*)d_in[2];
    const float* Wq          = (const float*)d_in[3];
    const float* bq          = (const float*)d_in[4];
    const float* conv_w      = (const float*)d_in[5];
    const float* conv_b      = (const float*)d_in[6];
    const float* Win         = (const float*)d_in[7];
    const float* b_in        = (const float*)d_in[8];
    const float* Wg          = (const float*)d_in[9];
    const float* bg          = (const float*)d_in[10];
    const float* Wi          = (const float*)d_in[11];
    const float* bi          = (const float*)d_in[12];
    const float* Wo          = (const float*)d_in[13];
    const float* bo          = (const float*)d_in[14];
    const float* ln_g        = (const float*)d_in[15];
    const float* ln_b        = (const float*)d_in[16];
    const float* mlp_w       = (const float*)d_in[17];
    const float* mlp_b       = (const float*)d_in[18];
    const float* Wout        = (const float*)d_in[19];
    const float* bout        = (const float*)d_in[20];
    float* out = (float*)d_out;

    const size_t NTOK = (size_t)B_ * T_;  // 65536
    char* p = (char*)d_ws;
    auto alloc = [&](size_t bytes) { void* r = (void*)p; p += (bytes + 255) & ~(size_t)255; return r; };
    __hip_bfloat16* featb = (__hip_bfloat16*)alloc(NTOK * FEATP_ * 2);
    float*          hfpre = (float*)alloc(NTOK * E_ * 4);
    __hip_bfloat16* hbA   = (__hip_bfloat16*)alloc(NTOK * H_ * 2);
    __hip_bfloat16* hbB   = (__hip_bfloat16*)alloc(NTOK * H_ * 2);
    float*          gates = (float*)alloc(NTOK * SS_ * 4);
    float*          drive = (float*)alloc(NTOK * SS_ * 4);
    __hip_bfloat16* states_bf = (__hip_bfloat16*)alloc(NTOK * SS_ * 2);
    float*          chA   = (float*)alloc((size_t)B_ * NCH_ * SS_ * 4);
    float*          chB   = (float*)alloc((size_t)B_ * NCH_ * SS_ * 4);
    float*          chH   = (float*)alloc((size_t)B_ * NCH_ * SS_ * 4);
    __hip_bfloat16* Wt_mlp= (__hip_bfloat16*)alloc(3 * 512 * 512 * 2);
    __hip_bfloat16* Wt_out= (__hip_bfloat16*)alloc(256 * 512 * 2);
    __hip_bfloat16* Wt_win= (__hip_bfloat16*)alloc(512 * FEATP_ * 2);
    __hip_bfloat16* Wt_gd = (__hip_bfloat16*)alloc(64 * 512 * 2);
    __hip_bfloat16* Wt_wo = (__hip_bfloat16*)alloc(512 * SS_ * 2);
    float*          Qtab  = (float*)alloc(256 * 64 * 4);
    __hip_bfloat16* Wt_wo2= (__hip_bfloat16*)alloc(32 * 512 * 2);

    k_prep_w<<<4288, 256, 0, stream>>>(mlp_w, Wout, Win, Wg, Wi, Wo, Wq, bq, emb_byte,
                                       Wt_mlp, Wt_out, Wt_win, Wt_gd, Wt_wo, Qtab, Wt_wo2);
    k_token_feats<<<NTOK / 4, 256, 0, stream>>>(chars, emb_byte, hash_tables, Qtab, featb, hfpre);
    k_conv<<<NTOK * E_ / 256, 256, 0, stream>>>(hfpre, conv_w, conv_b, featb);
    k_win256<<<512, 512, 0, stream>>>(featb, Wt_win, b_in, hbA);
    k_gates_mfma<<<NTOK / 256, 256, 0, stream>>>(hbA, Wt_gd, bg, bi, gates, drive);
    k_chunk_ab<<<B_ * NCH_ * SS_ / 256, 256, 0, stream>>>(gates, drive, chA, chB);
    k_chunk_scan<<<1, 256, 0, stream>>>(chA, chB, chH);
    k_states<<<B_ * NCH_ * SS_ / 256, 256, 0, stream>>>(gates, drive, chH, states_bf);
    k_wln<<<NTOK / 32, 256, 0, stream>>>(states_bf, Wt_wo2, bo, hbA, ln_g, ln_b, hbB);
    k_mlp256<<<512, 512, 0, stream>>>(hbB, Wt_mlp, mlp_b, hbA);
    k_mlp256<<<512, 512, 0, stream>>>(hbA, Wt_mlp + 262144, mlp_b + 512, hbB);
    k_mlp256<<<512, 512, 0, stream>>>(hbB, Wt_mlp + 524288, mlp_b + 1024, hbA);
    k_out256<<<256, 512, 0, stream>>>(hbA, Wt_out, bout, out);
}